// Round 4
// baseline (1084.977 us; speedup 1.0000x reference)
//
#include <hip/hip_runtime.h>
#include <stdint.h>

// NNAKF round 4: latency-spine attack. r3 proved wall = 512 x per-step critical
// path (co-residency was neutral). New structure: ONE barrier/step, gates stay
// in registers (pointwise fused into GEMM wave), h ping-pong LDS, fc A-frags
// reused as next GEMM A-frags, DPP for torus shuffles, packed-f16 sigma via
// shuffles (no LDS round-trip), Qt column in registers, all div -> v_rcp_f32.

#define DTc  0.1f
#define Q0V  0.01f      // PROCESS_NOISE_STD^2
#define RV   0.25f      // MEAS_NOISE_STD^2

typedef __bf16 bf16x8 __attribute__((ext_vector_type(8)));
typedef float  f32x4  __attribute__((ext_vector_type(4)));

__device__ __forceinline__ unsigned short f2bf(float f) {
    union { float f; unsigned int ui; } c; c.f = f;
    unsigned int u = c.ui;
    return (unsigned short)((u + 0x7FFFu + ((u >> 16) & 1u)) >> 16);   // RNE
}
__device__ __forceinline__ bf16x8 cvt8(float4 a, float4 b) {
    union { unsigned short us[8]; bf16x8 v; } r;
    r.us[0] = f2bf(a.x); r.us[1] = f2bf(a.y); r.us[2] = f2bf(a.z); r.us[3] = f2bf(a.w);
    r.us[4] = f2bf(b.x); r.us[5] = f2bf(b.y); r.us[6] = f2bf(b.z); r.us[7] = f2bf(b.w);
    return r.v;
}
__device__ __forceinline__ float rcpf(float x)  { return __builtin_amdgcn_rcpf(x); }
__device__ __forceinline__ float sigmf(float x) { return rcpf(1.0f + __expf(-x)); }
__device__ __forceinline__ float tanhf_(float x){ return 1.0f - 2.0f * rcpf(__expf(2.0f * x) + 1.0f); }

// DPP cross-lane (VALU-latency, replaces ds_bpermute on the predict chain)
#define DPP_ROR8   0x128   // row_ror:8  : lane gets value of lane^8 within row16
#define DPP_QUAD23 0x4E    // quad_perm [2,3,0,1]: lane j gets (j+2)&3 within quad
template<int CTRL>
__device__ __forceinline__ float dppf(float x) {
    return __builtin_bit_cast(float,
        __builtin_amdgcn_update_dpp(0, __builtin_bit_cast(int, x), CTRL, 0xF, 0xF, true));
}

__global__ __launch_bounds__(256, 2) void nnakf_kernel(
    const float* __restrict__ meas,   // [1024][512][2] f32
    const float* __restrict__ Qt,     // [10][4][4]
    const float* __restrict__ Wih,    // [512][2]
    const float* __restrict__ Whh,    // [512][128]
    const float* __restrict__ bih,    // [512]
    const float* __restrict__ bhh,    // [512]
    const float* __restrict__ Wfc,    // [10][128]
    const float* __restrict__ bfc,    // [10]
    float* __restrict__ out)          // [1024][512][4] f32
{
    __shared__ float          meas_s[2 * 1024];   // [b][t*2+c]
    __shared__ float2         wih_s[512];         // W_ih rows
    __shared__ unsigned short hbuf[2 * 320];      // ping-pong h bf16, row stride 160

    const int tid  = threadIdx.x;
    const int w    = tid >> 6;
    const int lane = tid & 63;
    const int idx  = lane & 15;
    const int q    = lane >> 4;
    const int qb   = q & 1;            // this lane's Kalman batch
    const int i    = idx >> 2, j = idx & 3;
    const int base = lane & 48;
    const int bg0  = blockIdx.x * 2;

    // ---- one-time init ----
    {
        const float4* g4 = (const float4*)(meas + (size_t)bg0 * 1024);
        float4* ms4 = (float4*)meas_s;
        for (int k = tid; k < 512; k += 256) ms4[k] = g4[k];
        const float4* wi4 = (const float4*)Wih;
        float4* ws4 = (float4*)wih_s;
        for (int k = tid; k < 256; k += 256) ws4[k] = wi4[k];
    }

    // W_hh as register B-fragments (bf16)
    bf16x8 wf[8][4];
    float  breg[8];
    const float4* whh4 = (const float4*)Whh;
    #pragma unroll
    for (int t8 = 0; t8 < 8; ++t8) {
        const int nb = ((t8 >> 1) << 7) + (w << 5) + ((t8 & 1) << 4);
        const int n  = nb + idx;
        breg[t8] = bih[n] + bhh[n];
        #pragma unroll
        for (int s = 0; s < 4; ++s) {
            float4 u0 = whh4[n * 32 + s * 8 + q * 2];
            float4 u1 = whh4[n * 32 + s * 8 + q * 2 + 1];
            wf[t8][s] = cvt8(u0, u1);   // B[k=s*32+q*8+jj][n]
        }
    }
    bf16x8 fcf[4];
    #pragma unroll
    for (int s = 0; s < 4; ++s) {
        float4 u0 = make_float4(0.f, 0.f, 0.f, 0.f), u1 = u0;
        if (idx < 10) {
            u0 = ((const float4*)Wfc)[idx * 32 + s * 8 + q * 2];
            u1 = ((const float4*)Wfc)[idx * 32 + s * 8 + q * 2 + 1];
        }
        fcf[s] = cvt8(u0, u1);
    }
    const float bfc_r = (idx < 10) ? bfc[idx] : 0.0f;

    // Qt column for this lane's matrix element (registers, not LDS)
    float qtc[10];
    #pragma unroll
    for (int n = 0; n < 10; ++n) qtc[n] = Qt[n * 16 + idx];

    // persistent per-lane state
    float P_reg = (i == j) ? 1.0f : 0.0f;
    float xn = 0.0f;
    float c4[4] = {0.f, 0.f, 0.f, 0.f};   // LSTM cell state: [hi][b], lanes<16
    bf16x8 af[4];                          // h(t-1) A-frags; h(-1)=0
    #pragma unroll
    for (int s = 0; s < 4; ++s) af[s] = __builtin_bit_cast(bf16x8, make_uint4(0, 0, 0, 0));

    __syncthreads();

    for (int t = 0; t < 512; ++t) {
        unsigned short* hw = &hbuf[(t & 1) * 320];
        const float2 zz = *(const float2*)&meas_s[qb * 1024 + 2 * t];

        // -------- recurrent GEMM (af = h(t-1), issues early, off-spine) ------
        f32x4 acc[8];
        #pragma unroll
        for (int t8 = 0; t8 < 8; ++t8)
            acc[t8] = (f32x4){breg[t8], breg[t8], breg[t8], breg[t8]};
        #pragma unroll
        for (int s = 0; s < 4; ++s)
            #pragma unroll
            for (int t8 = 0; t8 < 8; ++t8)
                acc[t8] = __builtin_amdgcn_mfma_f32_16x16x32_bf16(af[s], wf[t8][s], acc[t8], 0, 0, 0);

        // -------- Kalman predict (spine; DPP instead of bpermute) ------------
        const float pi2j  = dppf<DPP_ROR8>(P_reg);
        const float pij2  = dppf<DPP_QUAD23>(P_reg);
        const float pi2j2 = dppf<DPP_QUAD23>(pi2j);
        float pp = P_reg;
        if (i < 2) pp += DTc * pi2j;
        if (j < 2) pp += DTc * pij2;
        if (i < 2 && j < 2) pp += DTc * DTc * pi2j2;
        if (i == j) pp += Q0V;
        const float Pp0 = pp;
        const float xi2 = dppf<DPP_ROR8>(xn);
        const float xp  = xn + ((i < 2) ? DTc * xi2 : 0.0f);
        const float xp0  = __shfl(xp, base + 0, 64);
        const float xp1  = __shfl(xp, base + 4, 64);
        const float pp00 = __shfl(Pp0, base + 0, 64);
        const float pp11 = __shfl(Pp0, base + 5, 64);
        const float in0 = zz.x - xp0;
        const float in1 = zz.y - xp1;
        const float In0 = in0 * in0 * rcpf(pp00 + RV);
        const float In1 = in1 * in1 * rcpf(pp11 + RV);
        const float In0o = __shfl(In0, lane ^ 16, 64);   // other batch's In
        const float In1o = __shfl(In1, lane ^ 16, 64);

        // -------- LSTM pointwise, in-register gates (lanes 0-15) -------------
        if (lane < 16) {
            #pragma unroll
            for (int hi = 0; hi < 2; ++hi) {
                float2 wg[4];
                #pragma unroll
                for (int g = 0; g < 4; ++g)
                    wg[g] = wih_s[g * 128 + w * 32 + hi * 16 + lane];
                #pragma unroll
                for (int b = 0; b < 2; ++b) {
                    const float I0 = b ? In0o : In0;
                    const float I1 = b ? In1o : In1;
                    float pre[4];
                    #pragma unroll
                    for (int g = 0; g < 4; ++g)
                        pre[g] = acc[2 * g + hi][b] + I0 * wg[g].x + I1 * wg[g].y;
                    const float cprev = c4[hi * 2 + b];
                    const float cn = sigmf(pre[1]) * cprev + sigmf(pre[0]) * tanhf_(pre[2]);
                    const float hn = sigmf(pre[3]) * tanhf_(cn);
                    c4[hi * 2 + b] = cn;
                    hw[b * 160 + w * 32 + hi * 16 + lane] = f2bf(hn);
                }
            }
        }
        __syncthreads();   // the ONLY barrier: publish h(t)

        // -------- fc GEMM on h(t); af regs carried into next GEMM ------------
        #pragma unroll
        for (int s = 0; s < 4; ++s)
            af[s] = __builtin_bit_cast(bf16x8,
                        *(const uint4*)&hw[(idx & 1) * 160 + s * 32 + q * 8]);
        f32x4 f0 = (f32x4){0.f, 0.f, 0.f, 0.f};
        f32x4 f1 = (f32x4){0.f, 0.f, 0.f, 0.f};
        f0 = __builtin_amdgcn_mfma_f32_16x16x32_bf16(af[0], fcf[0], f0, 0, 0, 0);
        f1 = __builtin_amdgcn_mfma_f32_16x16x32_bf16(af[1], fcf[1], f1, 0, 0, 0);
        f0 = __builtin_amdgcn_mfma_f32_16x16x32_bf16(af[2], fcf[2], f0, 0, 0, 0);
        f1 = __builtin_amdgcn_mfma_f32_16x16x32_bf16(af[3], fcf[3], f1, 0, 0, 0);
        const f32x4 facc = f0 + f1;
        // rows alternate batches (A rows = idx&1) -> every lane has both batches
        const float sg0 = sigmf(facc[0] + bfc_r);   // batch 0, n = idx
        const float sg1 = sigmf(facc[1] + bfc_r);   // batch 1, n = idx
        const int pk = __builtin_bit_cast(int, __builtin_amdgcn_cvt_pkrtz(sg0, sg1));

        // -------- Q_adapt dot via 10 packed shuffles + register Qt -----------
        float dot = 0.0f;
        #pragma unroll
        for (int n = 0; n < 10; ++n) {
            const unsigned up = (unsigned)__shfl(pk, base + n, 64);
            const unsigned h16 = qb ? (up >> 16) : (up & 0xFFFFu);
            const _Float16 hf = __builtin_bit_cast(_Float16, (unsigned short)h16);
            dot += (float)hf * qtc[n];
        }
        const float Pp = Pp0 + dot;

        // -------- Kalman update ---------------------------------------------
        const float s00 = __shfl(Pp, base + 0, 64) + RV;
        const float s01 = __shfl(Pp, base + 1, 64);
        const float s10 = __shfl(Pp, base + 4, 64);
        const float s11 = __shfl(Pp, base + 5, 64) + RV;
        const float pi0 = __shfl(Pp, base + (i << 2), 64);
        const float pi1 = __shfl(Pp, base + (i << 2) + 1, 64);
        const float p0j = __shfl(Pp, base + j, 64);
        const float p1j = __shfl(Pp, base + 4 + j, 64);
        const float rdet = rcpf(s00 * s11 - s01 * s10);
        const float Ki0 = (pi0 * s11 - pi1 * s10) * rdet;
        const float Ki1 = (pi1 * s00 - pi0 * s01) * rdet;
        xn    = xp + Ki0 * in0 + Ki1 * in1;
        P_reg = Pp - (Ki0 * p0j + Ki1 * p1j);

        // -------- output (wave 0 only; off the next step's spine) ------------
        const float x1 = __shfl(xn, base + 4, 64);
        const float x2 = __shfl(xn, base + 8, 64);
        const float x3 = __shfl(xn, base + 12, 64);
        if (w == 0 && lane < 32 && idx == 0) {
            float4* o = (float4*)out;
            o[(size_t)(bg0 + qb) * 512 + t] = make_float4(xn, x1, x2, x3);
        }
    }
}

extern "C" void kernel_launch(void* const* d_in, const int* in_sizes, int n_in,
                              void* d_out, int out_size, void* d_ws, size_t ws_size,
                              hipStream_t stream) {
    (void)in_sizes; (void)n_in; (void)out_size; (void)d_ws; (void)ws_size;
    nnakf_kernel<<<512, 256, 0, stream>>>(
        (const float*)d_in[0],  // measurements
        (const float*)d_in[1],  // Q_tilde
        (const float*)d_in[2],  // W_ih
        (const float*)d_in[3],  // W_hh
        (const float*)d_in[4],  // b_ih
        (const float*)d_in[5],  // b_hh
        (const float*)d_in[6],  // W_fc
        (const float*)d_in[7],  // b_fc
        (float*)d_out);
}

// Round 5
// 721.241 us; speedup vs baseline: 1.5043x; 1.5043x over previous
//
#include <hip/hip_runtime.h>
#include <stdint.h>

// NNAKF round 5: crossbar-hop elimination. r3/r4 showed wall = 512 x dependent
// LDS-crossbar hops. Kalman now column-per-lane (lane j holds P[:,j] of batch
// (lane>>2)&3): all cross-lane ops are quad_perm DPP (~5cyc VALU) instead of
// ds_bpermute (~120cyc). Qt cols in 40 VGPRs. Sigma: one per-wave LDS
// broadcast. 4 batches/block, grid=256 (1 block/CU). Pointwise balanced
// (64 lanes x 2 cells), thread batch == lane Kalman batch -> In needs no comms.

#define DTc  0.1f
#define Q0V  0.01f      // PROCESS_NOISE_STD^2
#define RV   0.25f      // MEAS_NOISE_STD^2

typedef __bf16 bf16x8 __attribute__((ext_vector_type(8)));
typedef float  f32x4  __attribute__((ext_vector_type(4)));

__device__ __forceinline__ unsigned short f2bf(float f) {
    union { float f; unsigned int ui; } c; c.f = f;
    unsigned int u = c.ui;
    return (unsigned short)((u + 0x7FFFu + ((u >> 16) & 1u)) >> 16);   // RNE
}
__device__ __forceinline__ bf16x8 cvt8(float4 a, float4 b) {
    union { unsigned short us[8]; bf16x8 v; } r;
    r.us[0] = f2bf(a.x); r.us[1] = f2bf(a.y); r.us[2] = f2bf(a.z); r.us[3] = f2bf(a.w);
    r.us[4] = f2bf(b.x); r.us[5] = f2bf(b.y); r.us[6] = f2bf(b.z); r.us[7] = f2bf(b.w);
    return r.v;
}
__device__ __forceinline__ float rcpf(float x)  { return __builtin_amdgcn_rcpf(x); }
__device__ __forceinline__ float sigmf(float x) { return rcpf(1.0f + __expf(-x)); }
__device__ __forceinline__ float tanhf_(float x){ return 1.0f - 2.0f * rcpf(__expf(2.0f * x) + 1.0f); }

// quad_perm DPP: lane l reads lane (quadbase + perm[l&3])
#define QP_ROT2  0x4E   // [2,3,0,1] : col (j+2)&3
#define QP_BC0   0x00   // [0,0,0,0] : broadcast quad-lane 0
#define QP_BC1   0x55   // [1,1,1,1] : broadcast quad-lane 1
template<int CTRL>
__device__ __forceinline__ float dppf(float x) {
    return __builtin_bit_cast(float,
        __builtin_amdgcn_update_dpp(0, __builtin_bit_cast(int, x), CTRL, 0xF, 0xF, true));
}

__global__ __launch_bounds__(256, 1) void nnakf_kernel(
    const float* __restrict__ meas,   // [1024][512][2] f32
    const float* __restrict__ Qt,     // [10][4][4]
    const float* __restrict__ Wih,    // [512][2]
    const float* __restrict__ Whh,    // [512][128]
    const float* __restrict__ bih,    // [512]
    const float* __restrict__ bhh,    // [512]
    const float* __restrict__ Wfc,    // [10][128]
    const float* __restrict__ bfc,    // [10]
    float* __restrict__ out)          // [1024][512][4] f32
{
    __shared__ float          meas_s[4 * 1024];   // [b][t*2+c]
    __shared__ float2         wih_s[512];
    __shared__ float          gates_s[512 * 4];   // [n][b]
    __shared__ unsigned short hbuf[2 * 4 * 160];  // ping-pong, [b] rows stride 160
    __shared__ float          sig_s[4 * 40];      // per-wave [w][n][b]

    const int tid  = threadIdx.x;
    const int w    = tid >> 6;
    const int lane = tid & 63;
    const int idx  = lane & 15;
    const int q    = lane >> 4;
    const int j    = lane & 3;          // Kalman column
    const int b    = (lane >> 2) & 3;   // batch (replicated over q and waves)
    const int bg0  = blockIdx.x * 4;

    // ---- one-time init ----
    {
        const float4* g4 = (const float4*)(meas + (size_t)bg0 * 1024);
        float4* ms4 = (float4*)meas_s;
        for (int k = tid; k < 1024; k += 256) ms4[k] = g4[k];
        const float4* wi4 = (const float4*)Wih;
        float4* ws4 = (float4*)wih_s;
        for (int k = tid; k < 256; k += 256) ws4[k] = wi4[k];
    }

    // W_hh / W_fc register B-fragments (bf16)
    bf16x8 wf[8][4];
    float  breg[8];
    const float4* whh4 = (const float4*)Whh;
    #pragma unroll
    for (int t8 = 0; t8 < 8; ++t8) {
        const int nb = ((t8 >> 1) << 7) + (w << 5) + ((t8 & 1) << 4);
        const int n  = nb + idx;
        breg[t8] = bih[n] + bhh[n];
        #pragma unroll
        for (int s = 0; s < 4; ++s) {
            float4 u0 = whh4[n * 32 + s * 8 + q * 2];
            float4 u1 = whh4[n * 32 + s * 8 + q * 2 + 1];
            wf[t8][s] = cvt8(u0, u1);
        }
    }
    bf16x8 fcf[4];
    #pragma unroll
    for (int s = 0; s < 4; ++s) {
        float4 u0 = make_float4(0.f, 0.f, 0.f, 0.f), u1 = u0;
        if (idx < 10) {
            u0 = ((const float4*)Wfc)[idx * 32 + s * 8 + q * 2];
            u1 = ((const float4*)Wfc)[idx * 32 + s * 8 + q * 2 + 1];
        }
        fcf[s] = cvt8(u0, u1);
    }
    const float bfc_r = (idx < 10) ? bfc[idx] : 0.0f;

    // Qt columns in registers: qreg[n][i] = Qt[n][i][j]  (this lane's col)
    float qreg[10][4];
    #pragma unroll
    for (int n = 0; n < 10; ++n)
        #pragma unroll
        for (int r = 0; r < 4; ++r) qreg[n][r] = Qt[n * 16 + r * 4 + j];

    // Kalman state, column-per-lane: P[r] = P[r][j] of batch b
    float P0 = (j == 0) ? 1.f : 0.f, P1 = (j == 1) ? 1.f : 0.f;
    float P2 = (j == 2) ? 1.f : 0.f, P3 = (j == 3) ? 1.f : 0.f;
    float x0 = 0.f, x1 = 0.f, x2 = 0.f, x3 = 0.f;
    float cst0 = 0.f, cst1 = 0.f;          // LSTM cell state (2 cells/thread)
    bf16x8 af[4];
    #pragma unroll
    for (int s = 0; s < 4; ++s) af[s] = __builtin_bit_cast(bf16x8, make_uint4(0, 0, 0, 0));
    // loop-carried predict results
    float ppc0, ppc1, ppc2, ppc3, xp0, xp1, inn0, inn1, In0, In1;

    __syncthreads();

    // ---- predict for t=0 (x=0, P=I) ----
    #define PREDICT(TT)                                                          \
    {                                                                            \
        const float fp0 = P0 + DTc * P2, fp1 = P1 + DTc * P3;                    \
        const float d0 = dppf<QP_ROT2>(P0), d1 = dppf<QP_ROT2>(P1);              \
        const float d2 = dppf<QP_ROT2>(P2), d3 = dppf<QP_ROT2>(P3);              \
        const float fq0 = d0 + DTc * d2, fq1 = d1 + DTc * d3;                    \
        const bool jl2 = (j < 2);                                                \
        ppc0 = fp0 + (jl2 ? DTc * fq0 : 0.f) + ((j == 0) ? Q0V : 0.f);           \
        ppc1 = fp1 + (jl2 ? DTc * fq1 : 0.f) + ((j == 1) ? Q0V : 0.f);           \
        ppc2 = P2  + (jl2 ? DTc * d2  : 0.f) + ((j == 2) ? Q0V : 0.f);           \
        ppc3 = P3  + (jl2 ? DTc * d3  : 0.f) + ((j == 3) ? Q0V : 0.f);           \
        xp0 = x0 + DTc * x2; xp1 = x1 + DTc * x3;                                \
        const float2 zz = *(const float2*)&meas_s[b * 1024 + 2 * (TT)];          \
        inn0 = zz.x - xp0; inn1 = zz.y - xp1;                                    \
        const float s000 = dppf<QP_BC0>(ppc0) + RV;                              \
        const float s011 = dppf<QP_BC1>(ppc1) + RV;                              \
        In0 = inn0 * inn0 * rcpf(s000);                                          \
        In1 = inn1 * inn1 * rcpf(s011);                                          \
    }
    PREDICT(0)

    const int hbase = (lane & 3) | (q << 2) | (w << 4);   // 0..63, per batch b

    for (int t = 0; t < 512; ++t) {
        // -------- recurrent GEMM on h(t-1) (af) ------------------------------
        f32x4 acc[8];
        #pragma unroll
        for (int t8 = 0; t8 < 8; ++t8)
            acc[t8] = (f32x4){breg[t8], breg[t8], breg[t8], breg[t8]};
        #pragma unroll
        for (int s = 0; s < 4; ++s)
            #pragma unroll
            for (int t8 = 0; t8 < 8; ++t8)
                acc[t8] = __builtin_amdgcn_mfma_f32_16x16x32_bf16(af[s], wf[t8][s], acc[t8], 0, 0, 0);
        // A rows replicate mod 4 -> C reg r = batch r for every lane; write q==0
        if (lane < 16) {
            #pragma unroll
            for (int t8 = 0; t8 < 8; ++t8) {
                const int nb = ((t8 >> 1) << 7) + (w << 5) + ((t8 & 1) << 4);
                *(f32x4*)&gates_s[(nb + lane) * 4] = acc[t8];
            }
        }
        __syncthreads();   // B1: gates visible

        // -------- pointwise LSTM: 2 cells (hh, b) per thread -----------------
        unsigned short* hw = &hbuf[(t & 1) * 640];
        #pragma unroll
        for (int u = 0; u < 2; ++u) {
            const int hh = hbase + (u << 6);
            float pre[4];
            #pragma unroll
            for (int g = 0; g < 4; ++g) {
                const float2 wp = wih_s[g * 128 + hh];
                pre[g] = gates_s[(g * 128 + hh) * 4 + b] + In0 * wp.x + In1 * wp.y;
            }
            const float cprev = u ? cst1 : cst0;
            const float cn = sigmf(pre[1]) * cprev + sigmf(pre[0]) * tanhf_(pre[2]);
            const float hn = sigmf(pre[3]) * tanhf_(cn);
            if (u) cst1 = cn; else cst0 = cn;
            hw[b * 160 + hh] = f2bf(hn);
        }
        __syncthreads();   // B2: h(t) visible

        // -------- read h(t) A-frags (serve fc(t) AND GEMM(t+1)) --------------
        #pragma unroll
        for (int s = 0; s < 4; ++s)
            af[s] = __builtin_bit_cast(bf16x8,
                        *(const uint4*)&hw[(idx & 3) * 160 + s * 32 + q * 8]);

        // -------- fc GEMM -> sigma (per-wave LDS broadcast, 1 hop) -----------
        f32x4 f0 = (f32x4){0.f, 0.f, 0.f, 0.f};
        f32x4 f1 = (f32x4){0.f, 0.f, 0.f, 0.f};
        f0 = __builtin_amdgcn_mfma_f32_16x16x32_bf16(af[0], fcf[0], f0, 0, 0, 0);
        f1 = __builtin_amdgcn_mfma_f32_16x16x32_bf16(af[1], fcf[1], f1, 0, 0, 0);
        f0 = __builtin_amdgcn_mfma_f32_16x16x32_bf16(af[2], fcf[2], f0, 0, 0, 0);
        f1 = __builtin_amdgcn_mfma_f32_16x16x32_bf16(af[3], fcf[3], f1, 0, 0, 0);
        if (lane < 10) {   // reg r = batch r (A rows replicate mod 4)
            const f32x4 fs = f0 + f1;
            f32x4 sg;
            sg[0] = sigmf(fs[0] + bfc_r); sg[1] = sigmf(fs[1] + bfc_r);
            sg[2] = sigmf(fs[2] + bfc_r); sg[3] = sigmf(fs[3] + bfc_r);
            *(f32x4*)&sig_s[w * 40 + lane * 4] = sg;   // [n][b]
        }
        // same-wave DS ordering: reads below see this wave's write
        float sn[10];
        #pragma unroll
        for (int n = 0; n < 10; ++n) sn[n] = sig_s[w * 40 + n * 4 + b];

        // -------- Kalman update (all DPP/local, zero crossbar hops) ----------
        float a0 = 0.f, a1 = 0.f, a2 = 0.f, a3 = 0.f;   // split 5+5 chains
        float e0 = 0.f, e1 = 0.f, e2 = 0.f, e3 = 0.f;
        #pragma unroll
        for (int n = 0; n < 5; ++n) {
            a0 += sn[n] * qreg[n][0]; a1 += sn[n] * qreg[n][1];
            a2 += sn[n] * qreg[n][2]; a3 += sn[n] * qreg[n][3];
        }
        #pragma unroll
        for (int n = 5; n < 10; ++n) {
            e0 += sn[n] * qreg[n][0]; e1 += sn[n] * qreg[n][1];
            e2 += sn[n] * qreg[n][2]; e3 += sn[n] * qreg[n][3];
        }
        const float pc0 = ppc0 + a0 + e0;   // P_pred[:,j] (this lane's col)
        const float pc1 = ppc1 + a1 + e1;
        const float pc2 = ppc2 + a2 + e2;
        const float pc3 = ppc3 + a3 + e3;
        // P_pred cols 0,1 broadcast within quad (8 DPP)
        const float ph00 = dppf<QP_BC0>(pc0), ph01 = dppf<QP_BC1>(pc0);
        const float ph10 = dppf<QP_BC0>(pc1), ph11 = dppf<QP_BC1>(pc1);
        const float ph20 = dppf<QP_BC0>(pc2), ph21 = dppf<QP_BC1>(pc2);
        const float ph30 = dppf<QP_BC0>(pc3), ph31 = dppf<QP_BC1>(pc3);
        const float s00 = ph00 + RV, s01 = ph01, s10 = ph10, s11 = ph11 + RV;
        const float rdet = rcpf(s00 * s11 - s01 * s10);
        const float K00 = (ph00 * s11 - ph01 * s10) * rdet, K01 = (ph01 * s00 - ph00 * s01) * rdet;
        const float K10 = (ph10 * s11 - ph11 * s10) * rdet, K11 = (ph11 * s00 - ph10 * s01) * rdet;
        const float K20 = (ph20 * s11 - ph21 * s10) * rdet, K21 = (ph21 * s00 - ph20 * s01) * rdet;
        const float K30 = (ph30 * s11 - ph31 * s10) * rdet, K31 = (ph31 * s00 - ph30 * s01) * rdet;
        x0 = xp0 + K00 * inn0 + K01 * inn1;
        x1 = xp1 + K10 * inn0 + K11 * inn1;
        x2 = x2  + K20 * inn0 + K21 * inn1;
        x3 = x3  + K30 * inn0 + K31 * inn1;
        // P_new[:,j] = P_pred[:,j] - K[:,0]*P_pred[0][j] - K[:,1]*P_pred[1][j]
        P0 = pc0 - K00 * pc0 - K01 * pc1;
        P1 = pc1 - K10 * pc0 - K11 * pc1;
        P2 = pc2 - K20 * pc0 - K21 * pc1;
        P3 = pc3 - K30 * pc0 - K31 * pc1;

        // -------- output x(t) (off-spine) ------------------------------------
        if (w == 0 && q == 0 && j == 0) {
            float4* o = (float4*)out;
            o[(size_t)(bg0 + b) * 512 + t] = make_float4(x0, x1, x2, x3);
        }

        // -------- predict(t+1) -> In(t+1) ------------------------------------
        const int tn = (t < 511) ? t + 1 : 511;
        PREDICT(tn)
    }
}

extern "C" void kernel_launch(void* const* d_in, const int* in_sizes, int n_in,
                              void* d_out, int out_size, void* d_ws, size_t ws_size,
                              hipStream_t stream) {
    (void)in_sizes; (void)n_in; (void)out_size; (void)d_ws; (void)ws_size;
    nnakf_kernel<<<256, 256, 0, stream>>>(
        (const float*)d_in[0],  // measurements
        (const float*)d_in[1],  // Q_tilde
        (const float*)d_in[2],  // W_ih
        (const float*)d_in[3],  // W_hh
        (const float*)d_in[4],  // b_ih
        (const float*)d_in[5],  // b_hh
        (const float*)d_in[6],  // W_fc
        (const float*)d_in[7],  // b_fc
        (float*)d_out);
}

// Round 6
// 589.136 us; speedup vs baseline: 1.8416x; 1.2242x over previous
//
#include <hip/hip_runtime.h>
#include <stdint.h>

// NNAKF round 6: gates never leave registers. MFMA A-rows replicate mod 4, so
// C row m = batch m&3 -> every lane holds ALL 4 batches of gates[n=nb(t8)+idx]
// in acc[t8][0..3]. Pointwise cell (hh = w*32+u*16+idx, b=q) therefore reads
// its gates from the thread's own acc regs: gates LDS round-trip + barrier B1
// deleted. Kalman batch=q (col j=lane&3, replicated x4 per 16-lane group) ->
// In is in-lane for pointwise, zero comms. W_ih in registers. ONE barrier/step
// (publish h). Spine: GEMM -> reg pointwise -> h store -> barrier -> af load.

#define DTc  0.1f
#define Q0V  0.01f      // PROCESS_NOISE_STD^2
#define RV   0.25f      // MEAS_NOISE_STD^2

typedef __bf16 bf16x8 __attribute__((ext_vector_type(8)));
typedef float  f32x4  __attribute__((ext_vector_type(4)));

__device__ __forceinline__ unsigned short f2bf(float f) {
    union { float f; unsigned int ui; } c; c.f = f;
    unsigned int u = c.ui;
    return (unsigned short)((u + 0x7FFFu + ((u >> 16) & 1u)) >> 16);   // RNE
}
__device__ __forceinline__ bf16x8 cvt8(float4 a, float4 b) {
    union { unsigned short us[8]; bf16x8 v; } r;
    r.us[0] = f2bf(a.x); r.us[1] = f2bf(a.y); r.us[2] = f2bf(a.z); r.us[3] = f2bf(a.w);
    r.us[4] = f2bf(b.x); r.us[5] = f2bf(b.y); r.us[6] = f2bf(b.z); r.us[7] = f2bf(b.w);
    return r.v;
}
__device__ __forceinline__ float rcpf(float x)  { return __builtin_amdgcn_rcpf(x); }
__device__ __forceinline__ float sigmf(float x) { return rcpf(1.0f + __expf(-x)); }
__device__ __forceinline__ float tanhf_(float x){ return 1.0f - 2.0f * rcpf(__expf(2.0f * x) + 1.0f); }

// quad_perm DPP within each aligned 4-lane quad
#define QP_ROT2  0x4E   // [2,3,0,1]
#define QP_BC0   0x00   // broadcast quad-lane 0
#define QP_BC1   0x55   // broadcast quad-lane 1
template<int CTRL>
__device__ __forceinline__ float dppf(float x) {
    return __builtin_bit_cast(float,
        __builtin_amdgcn_update_dpp(0, __builtin_bit_cast(int, x), CTRL, 0xF, 0xF, true));
}
// select batch component (3 cndmask, masks hoisted by compiler)
__device__ __forceinline__ float selq(f32x4 v, int q) {
    float r = v[0];
    r = (q == 1) ? v[1] : r;
    r = (q == 2) ? v[2] : r;
    r = (q == 3) ? v[3] : r;
    return r;
}

__global__ __launch_bounds__(256, 1) void nnakf_kernel(
    const float* __restrict__ meas,   // [1024][512][2] f32
    const float* __restrict__ Qt,     // [10][4][4]
    const float* __restrict__ Wih,    // [512][2]
    const float* __restrict__ Whh,    // [512][128]
    const float* __restrict__ bih,    // [512]
    const float* __restrict__ bhh,    // [512]
    const float* __restrict__ Wfc,    // [10][128]
    const float* __restrict__ bfc,    // [10]
    float* __restrict__ out)          // [1024][512][4] f32
{
    __shared__ float          meas_s[4 * 1024];   // [b][t*2+c]
    __shared__ unsigned short hbuf[2 * 4 * 160];  // ping-pong h bf16, row stride 160
    __shared__ float          sig_s[4 * 40];      // per-wave [w][n][b]

    const int tid  = threadIdx.x;
    const int w    = tid >> 6;
    const int lane = tid & 63;
    const int idx  = lane & 15;
    const int q    = lane >> 4;         // batch (Kalman + pointwise + meas)
    const int j    = lane & 3;          // Kalman column (replicated x4 in group)
    const int bg0  = blockIdx.x * 4;

    // ---- one-time init ----
    {
        const float4* g4 = (const float4*)(meas + (size_t)bg0 * 1024);
        float4* ms4 = (float4*)meas_s;
        for (int k = tid; k < 1024; k += 256) ms4[k] = g4[k];
    }

    // W_hh / W_fc register B-fragments (bf16)
    bf16x8 wf[8][4];
    float  breg[8];
    const float4* whh4 = (const float4*)Whh;
    #pragma unroll
    for (int t8 = 0; t8 < 8; ++t8) {
        const int nb = ((t8 >> 1) << 7) + (w << 5) + ((t8 & 1) << 4);
        const int n  = nb + idx;
        breg[t8] = bih[n] + bhh[n];
        #pragma unroll
        for (int s = 0; s < 4; ++s) {
            float4 u0 = whh4[n * 32 + s * 8 + q * 2];
            float4 u1 = whh4[n * 32 + s * 8 + q * 2 + 1];
            wf[t8][s] = cvt8(u0, u1);   // B[k=s*32+q*8+e][n]
        }
    }
    bf16x8 fcf[4];
    #pragma unroll
    for (int s = 0; s < 4; ++s) {
        float4 u0 = make_float4(0.f, 0.f, 0.f, 0.f), u1 = u0;
        if (idx < 10) {
            u0 = ((const float4*)Wfc)[idx * 32 + s * 8 + q * 2];
            u1 = ((const float4*)Wfc)[idx * 32 + s * 8 + q * 2 + 1];
        }
        fcf[s] = cvt8(u0, u1);
    }
    const float bfc_r = (idx < 10) ? bfc[idx] : 0.0f;

    // W_ih rows for this thread's 2 cells x 4 gates (loop-invariant, registers)
    float2 wihr[2][4];
    #pragma unroll
    for (int u = 0; u < 2; ++u)
        #pragma unroll
        for (int g = 0; g < 4; ++g)
            wihr[u][g] = ((const float2*)Wih)[g * 128 + w * 32 + u * 16 + idx];

    // Qt columns: qreg[n][r] = Qt[n][r][j]
    float qreg[10][4];
    #pragma unroll
    for (int n = 0; n < 10; ++n)
        #pragma unroll
        for (int r = 0; r < 4; ++r) qreg[n][r] = Qt[n * 16 + r * 4 + j];

    // Kalman state, column-per-lane: P[r] = P[r][j] of batch q; full x per lane
    float P0 = (j == 0) ? 1.f : 0.f, P1 = (j == 1) ? 1.f : 0.f;
    float P2 = (j == 2) ? 1.f : 0.f, P3 = (j == 3) ? 1.f : 0.f;
    float x0 = 0.f, x1 = 0.f, x2 = 0.f, x3 = 0.f;
    float cst0 = 0.f, cst1 = 0.f;          // LSTM cell state (2 cells/thread)
    bf16x8 af[4];
    #pragma unroll
    for (int s = 0; s < 4; ++s) af[s] = __builtin_bit_cast(bf16x8, make_uint4(0, 0, 0, 0));
    float ppc0, ppc1, ppc2, ppc3, xp0, xp1, inn0, inn1, In0, In1;

    __syncthreads();   // meas_s ready

    #define PREDICT(TT)                                                          \
    {                                                                            \
        const float fp0 = P0 + DTc * P2, fp1 = P1 + DTc * P3;                    \
        const float d0 = dppf<QP_ROT2>(P0), d1 = dppf<QP_ROT2>(P1);              \
        const float d2 = dppf<QP_ROT2>(P2), d3 = dppf<QP_ROT2>(P3);              \
        const float fq0 = d0 + DTc * d2, fq1 = d1 + DTc * d3;                    \
        const bool jl2 = (j < 2);                                                \
        ppc0 = fp0 + (jl2 ? DTc * fq0 : 0.f) + ((j == 0) ? Q0V : 0.f);           \
        ppc1 = fp1 + (jl2 ? DTc * fq1 : 0.f) + ((j == 1) ? Q0V : 0.f);           \
        ppc2 = P2  + (jl2 ? DTc * d2  : 0.f) + ((j == 2) ? Q0V : 0.f);           \
        ppc3 = P3  + (jl2 ? DTc * d3  : 0.f) + ((j == 3) ? Q0V : 0.f);           \
        xp0 = x0 + DTc * x2; xp1 = x1 + DTc * x3;                                \
        const float2 zz = *(const float2*)&meas_s[q * 1024 + 2 * (TT)];          \
        inn0 = zz.x - xp0; inn1 = zz.y - xp1;                                    \
        const float s000 = dppf<QP_BC0>(ppc0) + RV;                              \
        const float s011 = dppf<QP_BC1>(ppc1) + RV;                              \
        In0 = inn0 * inn0 * rcpf(s000);                                          \
        In1 = inn1 * inn1 * rcpf(s011);                                          \
    }
    PREDICT(0)

    for (int t = 0; t < 512; ++t) {
        // -------- recurrent GEMM on h(t-1): gates stay in acc regs -----------
        f32x4 acc[8];
        #pragma unroll
        for (int t8 = 0; t8 < 8; ++t8)
            acc[t8] = (f32x4){breg[t8], breg[t8], breg[t8], breg[t8]};
        #pragma unroll
        for (int s = 0; s < 4; ++s)
            #pragma unroll
            for (int t8 = 0; t8 < 8; ++t8)
                acc[t8] = __builtin_amdgcn_mfma_f32_16x16x32_bf16(af[s], wf[t8][s], acc[t8], 0, 0, 0);

        // -------- pointwise LSTM from own registers: cells (w*32+u*16+idx, q)
        unsigned short* hw = &hbuf[(t & 1) * 640];
        #pragma unroll
        for (int u = 0; u < 2; ++u) {
            float pre[4];
            #pragma unroll
            for (int g = 0; g < 4; ++g)
                pre[g] = selq(acc[2 * g + u], q) + In0 * wihr[u][g].x + In1 * wihr[u][g].y;
            const float cprev = u ? cst1 : cst0;
            const float cn = sigmf(pre[1]) * cprev + sigmf(pre[0]) * tanhf_(pre[2]);
            const float hn = sigmf(pre[3]) * tanhf_(cn);
            if (u) cst1 = cn; else cst0 = cn;
            hw[q * 160 + w * 32 + u * 16 + idx] = f2bf(hn);
        }
        __syncthreads();   // the ONLY barrier: publish h(t)

        // -------- h(t) A-frags (serve fc(t) AND GEMM(t+1)) -------------------
        #pragma unroll
        for (int s = 0; s < 4; ++s)
            af[s] = __builtin_bit_cast(bf16x8,
                        *(const uint4*)&hw[(idx & 3) * 160 + s * 32 + q * 8]);

        // -------- fc GEMM -> sigma (per-wave LDS broadcast, 1 hop) -----------
        f32x4 f0 = (f32x4){0.f, 0.f, 0.f, 0.f};
        f32x4 f1 = (f32x4){0.f, 0.f, 0.f, 0.f};
        f0 = __builtin_amdgcn_mfma_f32_16x16x32_bf16(af[0], fcf[0], f0, 0, 0, 0);
        f1 = __builtin_amdgcn_mfma_f32_16x16x32_bf16(af[1], fcf[1], f1, 0, 0, 0);
        f0 = __builtin_amdgcn_mfma_f32_16x16x32_bf16(af[2], fcf[2], f0, 0, 0, 0);
        f1 = __builtin_amdgcn_mfma_f32_16x16x32_bf16(af[3], fcf[3], f1, 0, 0, 0);
        if (lane < 10) {   // reg r = batch r (A rows replicate mod 4)
            const f32x4 fs = f0 + f1;
            f32x4 sg;
            sg[0] = sigmf(fs[0] + bfc_r); sg[1] = sigmf(fs[1] + bfc_r);
            sg[2] = sigmf(fs[2] + bfc_r); sg[3] = sigmf(fs[3] + bfc_r);
            *(f32x4*)&sig_s[w * 40 + lane * 4] = sg;   // [n][b]
        }
        float sn[10];   // same-wave DS ordering: sees this wave's write
        #pragma unroll
        for (int n = 0; n < 10; ++n) sn[n] = sig_s[w * 40 + n * 4 + q];

        // -------- Kalman update (DPP/local only) -----------------------------
        float a0 = 0.f, a1 = 0.f, a2 = 0.f, a3 = 0.f;
        float e0 = 0.f, e1 = 0.f, e2 = 0.f, e3 = 0.f;
        #pragma unroll
        for (int n = 0; n < 5; ++n) {
            a0 += sn[n] * qreg[n][0]; a1 += sn[n] * qreg[n][1];
            a2 += sn[n] * qreg[n][2]; a3 += sn[n] * qreg[n][3];
        }
        #pragma unroll
        for (int n = 5; n < 10; ++n) {
            e0 += sn[n] * qreg[n][0]; e1 += sn[n] * qreg[n][1];
            e2 += sn[n] * qreg[n][2]; e3 += sn[n] * qreg[n][3];
        }
        const float pc0 = ppc0 + a0 + e0;   // P_pred[:,j]
        const float pc1 = ppc1 + a1 + e1;
        const float pc2 = ppc2 + a2 + e2;
        const float pc3 = ppc3 + a3 + e3;
        const float ph00 = dppf<QP_BC0>(pc0), ph01 = dppf<QP_BC1>(pc0);
        const float ph10 = dppf<QP_BC0>(pc1), ph11 = dppf<QP_BC1>(pc1);
        const float ph20 = dppf<QP_BC0>(pc2), ph21 = dppf<QP_BC1>(pc2);
        const float ph30 = dppf<QP_BC0>(pc3), ph31 = dppf<QP_BC1>(pc3);
        const float s00 = ph00 + RV, s01 = ph01, s10 = ph10, s11 = ph11 + RV;
        const float rdet = rcpf(s00 * s11 - s01 * s10);
        const float K00 = (ph00 * s11 - ph01 * s10) * rdet, K01 = (ph01 * s00 - ph00 * s01) * rdet;
        const float K10 = (ph10 * s11 - ph11 * s10) * rdet, K11 = (ph11 * s00 - ph10 * s01) * rdet;
        const float K20 = (ph20 * s11 - ph21 * s10) * rdet, K21 = (ph21 * s00 - ph20 * s01) * rdet;
        const float K30 = (ph30 * s11 - ph31 * s10) * rdet, K31 = (ph31 * s00 - ph30 * s01) * rdet;
        x0 = xp0 + K00 * inn0 + K01 * inn1;
        x1 = xp1 + K10 * inn0 + K11 * inn1;
        x2 = x2  + K20 * inn0 + K21 * inn1;
        x3 = x3  + K30 * inn0 + K31 * inn1;
        P0 = pc0 - K00 * pc0 - K01 * pc1;
        P1 = pc1 - K10 * pc0 - K11 * pc1;
        P2 = pc2 - K20 * pc0 - K21 * pc1;
        P3 = pc3 - K30 * pc0 - K31 * pc1;

        // -------- output x(t): lane j==0 of wave 0 holds full x for batch q --
        if (w == 0 && idx == 0) {
            float4* o = (float4*)out;
            o[(size_t)(bg0 + q) * 512 + t] = make_float4(x0, x1, x2, x3);
        }

        // -------- predict(t+1) -> In(t+1) ------------------------------------
        const int tn = (t < 511) ? t + 1 : 511;
        PREDICT(tn)
    }
}

extern "C" void kernel_launch(void* const* d_in, const int* in_sizes, int n_in,
                              void* d_out, int out_size, void* d_ws, size_t ws_size,
                              hipStream_t stream) {
    (void)in_sizes; (void)n_in; (void)out_size; (void)d_ws; (void)ws_size;
    nnakf_kernel<<<256, 256, 0, stream>>>(
        (const float*)d_in[0],  // measurements
        (const float*)d_in[1],  // Q_tilde
        (const float*)d_in[2],  // W_ih
        (const float*)d_in[3],  // W_hh
        (const float*)d_in[4],  // b_ih
        (const float*)d_in[5],  // b_hh
        (const float*)d_in[6],  // W_fc
        (const float*)d_in[7],  // b_fc
        (float*)d_out);
}

// Round 8
// 539.038 us; speedup vs baseline: 2.0128x; 1.0929x over previous
//
#include <hip/hip_runtime.h>
#include <stdint.h>

// NNAKF round 7 (resubmit after infra flake): row-replicated A-layout +
// step software-pipelining.
// A rows m -> batch m>>2 (h replicated x4 per row group) => C reg r = batch q
// for every lane: selq eliminated everywhere; fc gives own-batch sigma (1
// sigmoid, 1 scalar LDS write). Step reordered: pointwise(t) -> barrier ->
// af -> fc -> sigma-write -> GEMM(t+1) [32 MFMAs hide sigma RT + fc pipe]
// -> sigma-read + Q_adapt dot -> Kalman update -> predict(t+1).

#define DTc  0.1f
#define Q0V  0.01f      // PROCESS_NOISE_STD^2
#define RV   0.25f      // MEAS_NOISE_STD^2

typedef __bf16 bf16x8 __attribute__((ext_vector_type(8)));
typedef float  f32x4  __attribute__((ext_vector_type(4)));

__device__ __forceinline__ unsigned short f2bf(float f) {
    union { float f; unsigned int ui; } c; c.f = f;
    unsigned int u = c.ui;
    return (unsigned short)((u + 0x7FFFu + ((u >> 16) & 1u)) >> 16);   // RNE
}
__device__ __forceinline__ bf16x8 cvt8(float4 a, float4 b) {
    union { unsigned short us[8]; bf16x8 v; } r;
    r.us[0] = f2bf(a.x); r.us[1] = f2bf(a.y); r.us[2] = f2bf(a.z); r.us[3] = f2bf(a.w);
    r.us[4] = f2bf(b.x); r.us[5] = f2bf(b.y); r.us[6] = f2bf(b.z); r.us[7] = f2bf(b.w);
    return r.v;
}
__device__ __forceinline__ float rcpf(float x)  { return __builtin_amdgcn_rcpf(x); }
__device__ __forceinline__ float sigmf(float x) { return rcpf(1.0f + __expf(-x)); }
__device__ __forceinline__ float tanhf_(float x){ return 1.0f - 2.0f * rcpf(__expf(2.0f * x) + 1.0f); }

#define QP_ROT2  0x4E   // quad_perm [2,3,0,1]
#define QP_BC0   0x00   // quad broadcast lane 0
#define QP_BC1   0x55   // quad broadcast lane 1
template<int CTRL>
__device__ __forceinline__ float dppf(float x) {
    return __builtin_bit_cast(float,
        __builtin_amdgcn_update_dpp(0, __builtin_bit_cast(int, x), CTRL, 0xF, 0xF, true));
}

__global__ __launch_bounds__(256, 1) void nnakf_kernel(
    const float* __restrict__ meas,   // [1024][512][2] f32
    const float* __restrict__ Qt,     // [10][4][4]
    const float* __restrict__ Wih,    // [512][2]
    const float* __restrict__ Whh,    // [512][128]
    const float* __restrict__ bih,    // [512]
    const float* __restrict__ bhh,    // [512]
    const float* __restrict__ Wfc,    // [10][128]
    const float* __restrict__ bfc,    // [10]
    float* __restrict__ out)          // [1024][512][4] f32
{
    __shared__ float          meas_s[4 * 1024];   // [b][t*2+c]
    __shared__ unsigned short hbuf[2 * 640];      // ping-pong h bf16, stride 160
    __shared__ float          sig_s[4 * 64];      // per-wave [w][q*16+n]

    const int tid  = threadIdx.x;
    const int w    = tid >> 6;
    const int lane = tid & 63;
    const int idx  = lane & 15;
    const int q    = lane >> 4;         // batch
    const int j    = lane & 3;          // Kalman column
    const int bg0  = blockIdx.x * 4;

    // ---- one-time init ----
    {
        const float4* g4 = (const float4*)(meas + (size_t)bg0 * 1024);
        float4* ms4 = (float4*)meas_s;
        for (int k = tid; k < 1024; k += 256) ms4[k] = g4[k];
    }

    // W_hh / W_fc register B-fragments (bf16)
    bf16x8 wf[8][4];
    float  breg[8];
    const float4* whh4 = (const float4*)Whh;
    #pragma unroll
    for (int t8 = 0; t8 < 8; ++t8) {
        const int nb = ((t8 >> 1) << 7) + (w << 5) + ((t8 & 1) << 4);
        const int n  = nb + idx;
        breg[t8] = bih[n] + bhh[n];
        #pragma unroll
        for (int s = 0; s < 4; ++s) {
            float4 u0 = whh4[n * 32 + s * 8 + q * 2];
            float4 u1 = whh4[n * 32 + s * 8 + q * 2 + 1];
            wf[t8][s] = cvt8(u0, u1);   // B[k=s*32+q*8+e][n]
        }
    }
    bf16x8 fcf[4];
    #pragma unroll
    for (int s = 0; s < 4; ++s) {
        float4 u0 = make_float4(0.f, 0.f, 0.f, 0.f), u1 = u0;
        if (idx < 10) {
            u0 = ((const float4*)Wfc)[idx * 32 + s * 8 + q * 2];
            u1 = ((const float4*)Wfc)[idx * 32 + s * 8 + q * 2 + 1];
        }
        fcf[s] = cvt8(u0, u1);
    }
    const float bfc_r = (idx < 10) ? bfc[idx] : 0.0f;

    // W_ih rows for this thread's 2 cells x 4 gates
    float2 wihr[2][4];
    #pragma unroll
    for (int u = 0; u < 2; ++u)
        #pragma unroll
        for (int g = 0; g < 4; ++g)
            wihr[u][g] = ((const float2*)Wih)[g * 128 + w * 32 + u * 16 + idx];

    // Qt columns: qreg[n][r] = Qt[n][r][j]
    float qreg[10][4];
    #pragma unroll
    for (int n = 0; n < 10; ++n)
        #pragma unroll
        for (int r = 0; r < 4; ++r) qreg[n][r] = Qt[n * 16 + r * 4 + j];

    // Kalman state (column-per-lane, replicated over idx>>2 and waves)
    float P0 = (j == 0) ? 1.f : 0.f, P1 = (j == 1) ? 1.f : 0.f;
    float P2 = (j == 2) ? 1.f : 0.f, P3 = (j == 3) ? 1.f : 0.f;
    float x0 = 0.f, x1 = 0.f, x2 = 0.f, x3 = 0.f;
    float cst0 = 0.f, cst1 = 0.f;
    float ppc0, ppc1, ppc2, ppc3, xp0, xp1, inn0, inn1, In0, In1;

    // acc(0): h(-1)=0 -> gates = bias
    f32x4 acc[8];
    #pragma unroll
    for (int t8 = 0; t8 < 8; ++t8)
        acc[t8] = (f32x4){breg[t8], breg[t8], breg[t8], breg[t8]};

    __syncthreads();   // meas_s ready

    #define PREDICT(TT)                                                          \
    {                                                                            \
        const float fp0 = P0 + DTc * P2, fp1 = P1 + DTc * P3;                    \
        const float d0 = dppf<QP_ROT2>(P0), d1 = dppf<QP_ROT2>(P1);              \
        const float d2 = dppf<QP_ROT2>(P2), d3 = dppf<QP_ROT2>(P3);              \
        const float fq0 = d0 + DTc * d2, fq1 = d1 + DTc * d3;                    \
        const bool jl2 = (j < 2);                                                \
        ppc0 = fp0 + (jl2 ? DTc * fq0 : 0.f) + ((j == 0) ? Q0V : 0.f);           \
        ppc1 = fp1 + (jl2 ? DTc * fq1 : 0.f) + ((j == 1) ? Q0V : 0.f);           \
        ppc2 = P2  + (jl2 ? DTc * d2  : 0.f) + ((j == 2) ? Q0V : 0.f);           \
        ppc3 = P3  + (jl2 ? DTc * d3  : 0.f) + ((j == 3) ? Q0V : 0.f);           \
        xp0 = x0 + DTc * x2; xp1 = x1 + DTc * x3;                                \
        const float2 zz = *(const float2*)&meas_s[q * 1024 + 2 * (TT)];          \
        inn0 = zz.x - xp0; inn1 = zz.y - xp1;                                    \
        const float s000 = dppf<QP_BC0>(ppc0) + RV;                              \
        const float s011 = dppf<QP_BC1>(ppc1) + RV;                              \
        In0 = inn0 * inn0 * rcpf(s000);                                          \
        In1 = inn1 * inn1 * rcpf(s011);                                          \
    }
    PREDICT(0)

    for (int t = 0; t < 512; ++t) {
        // -------- pointwise LSTM(t): gates in own regs (acc[.][0] = batch q) -
        unsigned short* hw = &hbuf[(t & 1) * 640];
        #pragma unroll
        for (int u = 0; u < 2; ++u) {
            float pre[4];
            #pragma unroll
            for (int g = 0; g < 4; ++g)
                pre[g] = acc[2 * g + u][0] + In0 * wihr[u][g].x + In1 * wihr[u][g].y;
            const float cprev = u ? cst1 : cst0;
            const float cn = sigmf(pre[1]) * cprev + sigmf(pre[0]) * tanhf_(pre[2]);
            const float hn = sigmf(pre[3]) * tanhf_(cn);
            if (u) cst1 = cn; else cst0 = cn;
            hw[q * 160 + w * 32 + u * 16 + idx] = f2bf(hn);
        }
        __syncthreads();   // publish h(t)

        // -------- h(t) A-frags: row m -> batch m>>2 --------------------------
        bf16x8 af[4];
        #pragma unroll
        for (int s = 0; s < 4; ++s)
            af[s] = __builtin_bit_cast(bf16x8,
                        *(const uint4*)&hw[(idx >> 2) * 160 + s * 32 + q * 8]);

        // -------- fc GEMM first (sigma critical path) ------------------------
        f32x4 f0 = (f32x4){0.f, 0.f, 0.f, 0.f};
        f32x4 f1 = (f32x4){0.f, 0.f, 0.f, 0.f};
        f0 = __builtin_amdgcn_mfma_f32_16x16x32_bf16(af[0], fcf[0], f0, 0, 0, 0);
        f1 = __builtin_amdgcn_mfma_f32_16x16x32_bf16(af[1], fcf[1], f1, 0, 0, 0);
        f0 = __builtin_amdgcn_mfma_f32_16x16x32_bf16(af[2], fcf[2], f0, 0, 0, 0);
        f1 = __builtin_amdgcn_mfma_f32_16x16x32_bf16(af[3], fcf[3], f1, 0, 0, 0);
        const f32x4 facc = f0 + f1;
        // facc[0] = sigma_pre[own batch q][n=idx]
        const float sg = sigmf(facc[0] + bfc_r);
        if (idx < 10) sig_s[w * 64 + q * 16 + idx] = sg;

        // -------- recurrent GEMM for t+1 (hides sigma RT + fc pipe) ----------
        #pragma unroll
        for (int t8 = 0; t8 < 8; ++t8)
            acc[t8] = (f32x4){breg[t8], breg[t8], breg[t8], breg[t8]};
        #pragma unroll
        for (int s = 0; s < 4; ++s)
            #pragma unroll
            for (int t8 = 0; t8 < 8; ++t8)
                acc[t8] = __builtin_amdgcn_mfma_f32_16x16x32_bf16(af[s], wf[t8][s], acc[t8], 0, 0, 0);

        // -------- sigma read (broadcast) + Q_adapt dot -----------------------
        float sn[10];
        #pragma unroll
        for (int n = 0; n < 10; ++n) sn[n] = sig_s[w * 64 + q * 16 + n];
        float a0 = 0.f, a1 = 0.f, a2 = 0.f, a3 = 0.f;
        float e0 = 0.f, e1 = 0.f, e2 = 0.f, e3 = 0.f;
        #pragma unroll
        for (int n = 0; n < 5; ++n) {
            a0 += sn[n] * qreg[n][0]; a1 += sn[n] * qreg[n][1];
            a2 += sn[n] * qreg[n][2]; a3 += sn[n] * qreg[n][3];
        }
        #pragma unroll
        for (int n = 5; n < 10; ++n) {
            e0 += sn[n] * qreg[n][0]; e1 += sn[n] * qreg[n][1];
            e2 += sn[n] * qreg[n][2]; e3 += sn[n] * qreg[n][3];
        }
        const float pc0 = ppc0 + a0 + e0;   // P_pred[:,j]
        const float pc1 = ppc1 + a1 + e1;
        const float pc2 = ppc2 + a2 + e2;
        const float pc3 = ppc3 + a3 + e3;

        // -------- Kalman update (DPP/local) ----------------------------------
        const float ph00 = dppf<QP_BC0>(pc0), ph01 = dppf<QP_BC1>(pc0);
        const float ph10 = dppf<QP_BC0>(pc1), ph11 = dppf<QP_BC1>(pc1);
        const float ph20 = dppf<QP_BC0>(pc2), ph21 = dppf<QP_BC1>(pc2);
        const float ph30 = dppf<QP_BC0>(pc3), ph31 = dppf<QP_BC1>(pc3);
        const float s00 = ph00 + RV, s01 = ph01, s10 = ph10, s11 = ph11 + RV;
        const float rdet = rcpf(s00 * s11 - s01 * s10);
        const float K00 = (ph00 * s11 - ph01 * s10) * rdet, K01 = (ph01 * s00 - ph00 * s01) * rdet;
        const float K10 = (ph10 * s11 - ph11 * s10) * rdet, K11 = (ph11 * s00 - ph10 * s01) * rdet;
        const float K20 = (ph20 * s11 - ph21 * s10) * rdet, K21 = (ph21 * s00 - ph20 * s01) * rdet;
        const float K30 = (ph30 * s11 - ph31 * s10) * rdet, K31 = (ph31 * s00 - ph30 * s01) * rdet;
        x0 = xp0 + K00 * inn0 + K01 * inn1;
        x1 = xp1 + K10 * inn0 + K11 * inn1;
        x2 = x2  + K20 * inn0 + K21 * inn1;
        x3 = x3  + K30 * inn0 + K31 * inn1;
        P0 = pc0 - K00 * pc0 - K01 * pc1;
        P1 = pc1 - K10 * pc0 - K11 * pc1;
        P2 = pc2 - K20 * pc0 - K21 * pc1;
        P3 = pc3 - K30 * pc0 - K31 * pc1;

        // -------- output x(t) ------------------------------------------------
        if (w == 0 && idx == 0) {
            float4* o = (float4*)out;
            o[(size_t)(bg0 + q) * 512 + t] = make_float4(x0, x1, x2, x3);
        }

        // -------- predict(t+1) -> In(t+1) ------------------------------------
        const int tn = (t < 511) ? t + 1 : 511;
        PREDICT(tn)
    }
}

extern "C" void kernel_launch(void* const* d_in, const int* in_sizes, int n_in,
                              void* d_out, int out_size, void* d_ws, size_t ws_size,
                              hipStream_t stream) {
    (void)in_sizes; (void)n_in; (void)out_size; (void)d_ws; (void)ws_size;
    nnakf_kernel<<<256, 256, 0, stream>>>(
        (const float*)d_in[0],  // measurements
        (const float*)d_in[1],  // Q_tilde
        (const float*)d_in[2],  // W_ih
        (const float*)d_in[3],  // W_hh
        (const float*)d_in[4],  // b_ih
        (const float*)d_in[5],  // b_hh
        (const float*)d_in[6],  // W_fc
        (const float*)d_in[7],  // b_fc
        (float*)d_out);
}